// Round 5
// baseline (392.097 us; speedup 1.0000x reference)
//
#include <hip/hip_runtime.h>
#include <hip/hip_bf16.h>

typedef unsigned short ushort_t;
typedef __attribute__((ext_vector_type(8))) short bf16x8;   // 8 bf16 = 4 VGPRs
typedef __attribute__((ext_vector_type(4))) float f32x4;    // 4 fp32 acc

#define MDIM 2048
#define NDIM 4096

__device__ __forceinline__ ushort_t to_bf16(float f) {
    __hip_bfloat16 h = __float2bfloat16(f);
    return *reinterpret_cast<ushort_t*>(&h);
}

// ---------------- prep: fp32 -> bf16 cast ----------------
__global__ void cast_bf16_kernel(const float* __restrict__ in, ushort_t* __restrict__ out, int n) {
    int i = blockIdx.x * blockDim.x + threadIdx.x;
    if (i < n) out[i] = to_bf16(in[i]);
}

// ---------------- prep: W[K][N] fp32 -> WT[N][K] bf16 ----------------
__global__ void transpose_cast_kernel(const float* __restrict__ W, ushort_t* __restrict__ WT,
                                      int K, int N) {
    __shared__ float tile[32][33];
    const int tx = threadIdx.x, ty = threadIdx.y;  // (32, 8)
    const int n0 = blockIdx.x * 32, k0 = blockIdx.y * 32;
#pragma unroll
    for (int r = 0; r < 4; ++r)
        tile[ty + r * 8][tx] = W[(size_t)(k0 + ty + r * 8) * N + n0 + tx];
    __syncthreads();
    const int t = ty * 32 + tx;
    const int nl = t >> 3;          // 0..31 : local n
    const int kc = (t & 7) * 4;     // 0..28 : k chunk of 4
    ushort4 o;
    o.x = to_bf16(tile[kc + 0][nl]);
    o.y = to_bf16(tile[kc + 1][nl]);
    o.z = to_bf16(tile[kc + 2][nl]);
    o.w = to_bf16(tile[kc + 3][nl]);
    *reinterpret_cast<ushort4*>(&WT[(size_t)(n0 + nl) * K + k0 + kc]) = o;
}

// ---------------- GEMM: C[M][N] = act(A[M][K] @ BT[N][K]^T + bias) ----------------
// 128x256 block tile, BK=32, 4 waves (2x2), wave tile 64x128 = 4x8 of
// mfma_f32_16x16x32_bf16. Rationale (R4 post-mortem): the 64x64-wave version is
// LDS-BW-bound (96 KB/CU-iter vs 155 cyc of MFMA). 64x128 wave tiles cut LDS
// reads/FLOP 1.33x and staging writes/FLOP 2x (72 KB/CU-iter). LDS is
// double-buffered (one barrier/iter; ds_writes of tile k+1 overlap MFMAs of
// tile k) + register prefetch of tile k+1 during compute. Grid 256 = 1
// block/CU. LDA=40 pad keeps b128 fragment reads conflict-free (2-way only).
template <typename OutT, bool RELU>
__global__ __launch_bounds__(256, 1) void gemm_bt(const ushort_t* __restrict__ A,
                                                  const ushort_t* __restrict__ BT,
                                                  const float* __restrict__ bias,
                                                  OutT* __restrict__ C, int Kdim) {
    __shared__ __align__(16) ushort_t As[2][128 * 40];  // 20 KB
    __shared__ __align__(16) ushort_t Bs[2][256 * 40];  // 40 KB

    const int t = threadIdx.x;
    const int m0 = blockIdx.y * 128;
    const int n0 = blockIdx.x * 256;
    const int lane = t & 63;
    const int wid = t >> 6;
    const int quad = lane >> 4;
    const int l16 = lane & 15;
    const int wm = (wid & 1) * 64;    // wave M offset
    const int wn = (wid >> 1) * 128;  // wave N offset

    f32x4 acc[4][8];
#pragma unroll
    for (int i = 0; i < 4; ++i)
#pragma unroll
        for (int j = 0; j < 8; ++j) acc[i][j] = (f32x4){0.f, 0.f, 0.f, 0.f};

    // staging: A 128x32 (512 16B-chunks) + B 256x32 (1024 chunks); 256 thr x 6
    const int row_a = t >> 2;  // 0..63
    const int cc = t & 3;      // 16B chunk within row

    const ushort_t* pA0 = A + (size_t)(m0 + row_a) * Kdim + cc * 8;
    const ushort_t* pA1 = pA0 + (size_t)64 * Kdim;
    const ushort_t* pB0 = BT + (size_t)(n0 + row_a) * Kdim + cc * 8;
    const ushort_t* pB1 = pB0 + (size_t)64 * Kdim;
    const ushort_t* pB2 = pB0 + (size_t)128 * Kdim;
    const ushort_t* pB3 = pB0 + (size_t)192 * Kdim;

    const int la0 = row_a * 40 + cc * 8;
    const int la1 = (row_a + 64) * 40 + cc * 8;
    const int lb0 = row_a * 40 + cc * 8;
    const int lb1 = (row_a + 64) * 40 + cc * 8;
    const int lb2 = (row_a + 128) * 40 + cc * 8;
    const int lb3 = (row_a + 192) * 40 + cc * 8;

    // prefetch tile 0 and write to buffer 0
    uint4 ra0 = *reinterpret_cast<const uint4*>(pA0);
    uint4 ra1 = *reinterpret_cast<const uint4*>(pA1);
    uint4 rb0 = *reinterpret_cast<const uint4*>(pB0);
    uint4 rb1 = *reinterpret_cast<const uint4*>(pB1);
    uint4 rb2 = *reinterpret_cast<const uint4*>(pB2);
    uint4 rb3 = *reinterpret_cast<const uint4*>(pB3);
    *reinterpret_cast<uint4*>(&As[0][la0]) = ra0;
    *reinterpret_cast<uint4*>(&As[0][la1]) = ra1;
    *reinterpret_cast<uint4*>(&Bs[0][lb0]) = rb0;
    *reinterpret_cast<uint4*>(&Bs[0][lb1]) = rb1;
    *reinterpret_cast<uint4*>(&Bs[0][lb2]) = rb2;
    *reinterpret_cast<uint4*>(&Bs[0][lb3]) = rb3;
    __syncthreads();

    int p = 0;
    for (int k0 = 0; k0 < Kdim; k0 += 32) {
        const bool more = (k0 + 32) < Kdim;
        // prefetch tile k+1 into regs (overlaps everything below)
        if (more) {
            ra0 = *reinterpret_cast<const uint4*>(pA0 + k0 + 32);
            ra1 = *reinterpret_cast<const uint4*>(pA1 + k0 + 32);
            rb0 = *reinterpret_cast<const uint4*>(pB0 + k0 + 32);
            rb1 = *reinterpret_cast<const uint4*>(pB1 + k0 + 32);
            rb2 = *reinterpret_cast<const uint4*>(pB2 + k0 + 32);
            rb3 = *reinterpret_cast<const uint4*>(pB3 + k0 + 32);
        }

        // fragments from buffer p
        bf16x8 af[4], bfr[8];
#pragma unroll
        for (int i = 0; i < 4; ++i)
            af[i] = *reinterpret_cast<const bf16x8*>(&As[p][(wm + i * 16 + l16) * 40 + quad * 8]);
#pragma unroll
        for (int j = 0; j < 8; ++j)
            bfr[j] = *reinterpret_cast<const bf16x8*>(&Bs[p][(wn + j * 16 + l16) * 40 + quad * 8]);

#pragma unroll
        for (int i = 0; i < 4; ++i)
#pragma unroll
            for (int j = 0; j < 8; ++j)
                acc[i][j] = __builtin_amdgcn_mfma_f32_16x16x32_bf16(af[i], bfr[j], acc[i][j], 0, 0, 0);

        // write tile k+1 into the other buffer (overlaps MFMAs above)
        if (more) {
            *reinterpret_cast<uint4*>(&As[p ^ 1][la0]) = ra0;
            *reinterpret_cast<uint4*>(&As[p ^ 1][la1]) = ra1;
            *reinterpret_cast<uint4*>(&Bs[p ^ 1][lb0]) = rb0;
            *reinterpret_cast<uint4*>(&Bs[p ^ 1][lb1]) = rb1;
            *reinterpret_cast<uint4*>(&Bs[p ^ 1][lb2]) = rb2;
            *reinterpret_cast<uint4*>(&Bs[p ^ 1][lb3]) = rb3;
        }
        __syncthreads();
        p ^= 1;
    }

    // epilogue: C/D layout col=lane&15, row=quad*4+reg
#pragma unroll
    for (int i = 0; i < 4; ++i) {
#pragma unroll
        for (int r = 0; r < 4; ++r) {
            const int grow = m0 + wm + i * 16 + quad * 4 + r;
#pragma unroll
            for (int j = 0; j < 8; ++j) {
                const int gcol = n0 + wn + j * 16 + l16;
                float v = acc[i][j][r] + bias[gcol];
                if (RELU) v = fmaxf(v, 0.0f);
                if constexpr (sizeof(OutT) == 2) {
                    C[(size_t)grow * NDIM + gcol] = to_bf16(v);
                } else {
                    C[(size_t)grow * NDIM + gcol] = v;
                }
            }
        }
    }
}

// ---------------- Sinkhorn, factored: P = diag(a) K diag(b) ----------------
// One wave per matrix; K register-resident both ways; pure VALU + readlane.
__device__ __forceinline__ float rdl(float v, int l) {
    return __uint_as_float(__builtin_amdgcn_readlane(__float_as_uint(v), l));
}

__global__ __launch_bounds__(64) void sinkhorn_kernel(float* __restrict__ PM) {
    __shared__ __align__(16) float T[64 * 65];  // one-time transpose staging
    const int l = threadIdx.x;
    float* base = PM + (size_t)blockIdx.x * 4096;

    float Kcol[64];  // Kcol[r] = K[r][l]
    float Krow[64];  // Krow[c] = K[l][c]
#pragma unroll
    for (int r = 0; r < 64; ++r)
        Kcol[r] = __expf(-base[r * 64 + l]);  // global /sum cancels in 1st row-norm
#pragma unroll
    for (int r = 0; r < 64; ++r)
        T[r * 65 + l] = Kcol[r];
    __syncthreads();
#pragma unroll
    for (int c = 0; c < 64; ++c)
        Krow[c] = T[l * 65 + c];

    float a = 0.0f, b = 1.0f;
    for (int it = 0; it < 1000; ++it) {
        float t1 = 0.0f;  // (K b)_row=l
#pragma unroll
        for (int c = 0; c < 64; ++c)
            t1 = fmaf(Krow[c], rdl(b, c), t1);
        a = 0.015625f / t1;  // r = 1/64

        float t2 = 0.0f;  // (K^T a)_col=l
#pragma unroll
        for (int r = 0; r < 64; ++r)
            t2 = fmaf(Kcol[r], rdl(a, r), t2);
        const float err = fabsf(b * t2 - 0.015625f);  // beta_c - c
        if (__ballot(err > 1e-6f) == 0ull) break;     // break BEFORE col-norm
        b = 0.015625f / t2;
    }

#pragma unroll
    for (int r = 0; r < 64; ++r)
        base[r * 64 + l] = rdl(a, r) * Kcol[r] * b;
}

extern "C" void kernel_launch(void* const* d_in, const int* in_sizes, int n_in,
                              void* d_out, int out_size, void* d_ws, size_t ws_size,
                              hipStream_t stream) {
    const float* z  = (const float*)d_in[0];
    const float* W1 = (const float*)d_in[1];
    const float* b1 = (const float*)d_in[2];
    const float* W2 = (const float*)d_in[3];
    const float* b2 = (const float*)d_in[4];
    const float* W3 = (const float*)d_in[5];
    const float* b3 = (const float*)d_in[6];
    float* out = (float*)d_out;
    char* ws = (char*)d_ws;

    // workspace layout (bytes)
    ushort_t* W2T = (ushort_t*)(ws + 0);                       // 32 MB
    ushort_t* W3T = (ushort_t*)(ws + (size_t)33554432);        // 32 MB
    ushort_t* C1b = (ushort_t*)(ws + (size_t)67108864);        // 16 MB
    ushort_t* C2b = (ushort_t*)(ws + (size_t)83886080);        // 16 MB
    ushort_t* Zb  = (ushort_t*)(ws + (size_t)100663296);       // 1 MB
    ushort_t* W1T = (ushort_t*)(ws + (size_t)101711872);       // 2 MB

    // prep
    cast_bf16_kernel<<<2048, 256, 0, stream>>>(z, Zb, MDIM * 256);
    transpose_cast_kernel<<<dim3(128, 8), dim3(32, 8), 0, stream>>>(W1, W1T, 256, 4096);
    transpose_cast_kernel<<<dim3(128, 128), dim3(32, 8), 0, stream>>>(W2, W2T, 4096, 4096);
    transpose_cast_kernel<<<dim3(128, 128), dim3(32, 8), 0, stream>>>(W3, W3T, 4096, 4096);

    // 3-layer MLP (bf16 MFMA, fp32 accum); layer 3 writes fp32 cost matrix into d_out
    gemm_bt<ushort_t, true><<<dim3(NDIM / 256, MDIM / 128), 256, 0, stream>>>(Zb, W1T, b1, C1b, 256);
    gemm_bt<ushort_t, true><<<dim3(NDIM / 256, MDIM / 128), 256, 0, stream>>>(C1b, W2T, b2, C2b, 4096);
    gemm_bt<float, false><<<dim3(NDIM / 256, MDIM / 128), 256, 0, stream>>>(C2b, W3T, b3, out, 4096);

    // Sinkhorn in-place on d_out (one wave per matrix, register-resident K)
    sinkhorn_kernel<<<2048, 64, 0, stream>>>(out);
}